// Round 3
// baseline (385.284 us; speedup 1.0000x reference)
//
#include <hip/hip_runtime.h>

// LogicGateNetwork: 5 layers of per-neuron 2-input soft logic gates.
// Activations kept TRANSPOSED ([dim][BATCH]) so per-neuron column gathers are
// coalesced contiguous row reads. Coefs computed inline per block (no ws).

#define NBATCH 2048

// GATE_COEF (16 gates x 4 coefficients), row-major.
__device__ __constant__ float GC_dev[64] = {
    0, 0, 0, 0,   0, 0, 0, 1,   0, 1, 0, -1,  0, 1, 0, 0,
    0, 0, 1, -1,  0, 0, 1, 0,   0, 1, 1, -2,  0, 1, 1, -1,
    1, -1, -1, 1, 1, -1, -1, 2, 1, 0, -1, 0,  1, 0, -1, 1,
    1, -1, 0, 0,  1, -1, 0, 1,  1, 0, 0, -1,  1, 0, 0, 0
};

__device__ __forceinline__ float bf2f(unsigned short b) {
    return __uint_as_float(((unsigned int)b) << 16);
}
__device__ __forceinline__ unsigned short f2bf(float f) {
    unsigned int u = __float_as_uint(f);
    u += 0x7FFFu + ((u >> 16) & 1u);   // round-to-nearest-even
    return (unsigned short)(u >> 16);
}
__device__ __forceinline__ float tof(float x) { return x; }
__device__ __forceinline__ float tof(unsigned short x) { return bf2f(x); }
template <typename T> __device__ __forceinline__ T fromf(float x);
template <> __device__ __forceinline__ float fromf<float>(float x) { return x; }
template <> __device__ __forceinline__ unsigned short fromf<unsigned short>(float x) { return f2bf(x); }

// coef = softmax(w_row) @ GATE_COEF (4 floats into sc[0..3]).
__device__ __forceinline__ void compute_coef(const float* __restrict__ wrow,
                                             float* __restrict__ sc) {
    float v[16];
#pragma unroll
    for (int g = 0; g < 16; ++g) v[g] = wrow[g];
    float m = v[0];
#pragma unroll
    for (int g = 1; g < 16; ++g) m = fmaxf(m, v[g]);
    float s = 0.f;
#pragma unroll
    for (int g = 0; g < 16; ++g) { v[g] = __expf(v[g] - m); s += v[g]; }
    float inv = 1.f / s;
    float c0 = 0.f, c1 = 0.f, c2 = 0.f, c3 = 0.f;
#pragma unroll
    for (int g = 0; g < 16; ++g) {
        c0 += v[g] * GC_dev[g * 4 + 0];
        c1 += v[g] * GC_dev[g * 4 + 1];
        c2 += v[g] * GC_dev[g * 4 + 2];
        c3 += v[g] * GC_dev[g * 4 + 3];
    }
    sc[0] = c0 * inv; sc[1] = c1 * inv; sc[2] = c2 * inv; sc[3] = c3 * inv;
}

// LDS-tiled transpose: in[rows][cols] -> out[cols][rows]. Block (32,8).
template <typename TI, typename TO>
__global__ void transpose_kernel(const TI* __restrict__ in, TO* __restrict__ out,
                                 int rows, int cols) {
    __shared__ float tile[32][33];  // +1 pad: no LDS bank conflicts
    int bx = blockIdx.x * 32, by = blockIdx.y * 32;
    int tx = threadIdx.x, ty = threadIdx.y;
#pragma unroll
    for (int i = 0; i < 32; i += 8) {
        int r = by + ty + i, c = bx + tx;
        if (r < rows && c < cols) tile[ty + i][tx] = tof(in[(size_t)r * cols + c]);
    }
    __syncthreads();
#pragma unroll
    for (int i = 0; i < 32; i += 8) {
        int oc = bx + ty + i;  // output row = input col
        int orr = by + tx;     // output col = input row
        if (oc < cols && orr < rows)
            out[(size_t)oc * rows + orr] = fromf<TO>(tile[tx][ty + i]);
    }
}

// One block per output neuron j; 512 threads cover the batch 4-wide.
// in/out: [dim][NBATCH] activations (fp32 or bf16 storage).
template <bool BF16>
__global__ __launch_bounds__(512) void logic_layer_kernel(
    const void* __restrict__ in_, void* __restrict__ out_,
    const int* __restrict__ ia, const int* __restrict__ ib,
    const float* __restrict__ w) {
    __shared__ float sc[4];
    int j = blockIdx.x;
    int t = threadIdx.x;  // 0..511
    if (t == 0) compute_coef(w + (size_t)j * 16, sc);
    int ja = ia[j];
    int jb = ib[j];

    float a[4], b[4];
    if constexpr (BF16) {
        const ushort4* ra = (const ushort4*)((const unsigned short*)in_ + (size_t)ja * NBATCH);
        const ushort4* rb = (const ushort4*)((const unsigned short*)in_ + (size_t)jb * NBATCH);
        ushort4 av = ra[t], bv = rb[t];
        a[0] = bf2f(av.x); a[1] = bf2f(av.y); a[2] = bf2f(av.z); a[3] = bf2f(av.w);
        b[0] = bf2f(bv.x); b[1] = bf2f(bv.y); b[2] = bf2f(bv.z); b[3] = bf2f(bv.w);
    } else {
        const float4* ra = (const float4*)((const float*)in_ + (size_t)ja * NBATCH);
        const float4* rb = (const float4*)((const float*)in_ + (size_t)jb * NBATCH);
        float4 av = ra[t], bv = rb[t];
        a[0] = av.x; a[1] = av.y; a[2] = av.z; a[3] = av.w;
        b[0] = bv.x; b[1] = bv.y; b[2] = bv.z; b[3] = bv.w;
    }
    __syncthreads();
    float c0 = sc[0], c1 = sc[1], c2 = sc[2], c3 = sc[3];

    float o[4];
#pragma unroll
    for (int k = 0; k < 4; ++k)
        o[k] = fmaf(c3, a[k] * b[k], fmaf(c2, b[k], fmaf(c1, a[k], c0)));

    if constexpr (BF16) {
        ushort4 ov = make_ushort4(f2bf(o[0]), f2bf(o[1]), f2bf(o[2]), f2bf(o[3]));
        ((ushort4*)((unsigned short*)out_ + (size_t)j * NBATCH))[t] = ov;
    } else {
        float4 ov = make_float4(o[0], o[1], o[2], o[3]);
        ((float4*)((float*)out_ + (size_t)j * NBATCH))[t] = ov;
    }
}

extern "C" void kernel_launch(void* const* d_in, const int* in_sizes, int n_in,
                              void* d_out, int out_size, void* d_ws, size_t ws_size,
                              hipStream_t stream) {
    // Input dict order: x, then (w_i, ia_i, ib_i) for i=0..4.
    const float* x = (const float*)d_in[0];
    const float* w[5];
    const int* ia[5];
    const int* ib[5];
    for (int i = 0; i < 5; ++i) {
        w[i]  = (const float*)d_in[1 + 3 * i];
        ia[i] = (const int*)d_in[2 + 3 * i];
        ib[i] = (const int*)d_in[3 + 3 * i];
    }

    char* ws = (char*)d_ws;
    const size_t bufBytesF = (size_t)16384 * NBATCH * sizeof(float);  // 128 MiB
    dim3 tb(32, 8);

    if (ws_size >= 2 * bufBytesF) {
        // ---- fp32 path: exactly 256 MiB of ws ----
        float* bufA = (float*)ws;
        float* bufB = (float*)(ws + bufBytesF);
        float* xT  = bufB;  // 64 MiB; bufB not written until layer 1
        float* h4T = bufA;  // 8 MiB; bufA dead after layer 3 reads it

        transpose_kernel<float, float><<<dim3(8192 / 32, NBATCH / 32), tb, 0, stream>>>(
            x, xT, NBATCH, 8192);
        logic_layer_kernel<false><<<16384, 512, 0, stream>>>(xT,   bufA, ia[0], ib[0], w[0]);
        logic_layer_kernel<false><<<16384, 512, 0, stream>>>(bufA, bufB, ia[1], ib[1], w[1]);
        logic_layer_kernel<false><<<16384, 512, 0, stream>>>(bufB, bufA, ia[2], ib[2], w[2]);
        logic_layer_kernel<false><<<16384, 512, 0, stream>>>(bufA, bufB, ia[3], ib[3], w[3]);
        logic_layer_kernel<false><<<1000,  512, 0, stream>>>(bufB, h4T,  ia[4], ib[4], w[4]);
        transpose_kernel<float, float><<<dim3(NBATCH / 32, (1000 + 31) / 32), tb, 0, stream>>>(
            h4T, (float*)d_out, 1000, NBATCH);
    } else {
        // ---- bf16 fallback: 128 MiB of ws ----
        const size_t bufBytesH = (size_t)16384 * NBATCH * sizeof(unsigned short);  // 64 MiB
        unsigned short* bufA = (unsigned short*)ws;
        unsigned short* bufB = (unsigned short*)(ws + bufBytesH);
        unsigned short* xT  = bufB;  // 32 MiB
        unsigned short* h4T = bufA;  // 4 MiB

        transpose_kernel<float, unsigned short><<<dim3(8192 / 32, NBATCH / 32), tb, 0, stream>>>(
            x, xT, NBATCH, 8192);
        logic_layer_kernel<true><<<16384, 512, 0, stream>>>(xT,   bufA, ia[0], ib[0], w[0]);
        logic_layer_kernel<true><<<16384, 512, 0, stream>>>(bufA, bufB, ia[1], ib[1], w[1]);
        logic_layer_kernel<true><<<16384, 512, 0, stream>>>(bufB, bufA, ia[2], ib[2], w[2]);
        logic_layer_kernel<true><<<16384, 512, 0, stream>>>(bufA, bufB, ia[3], ib[3], w[3]);
        logic_layer_kernel<true><<<1000,  512, 0, stream>>>(bufB, h4T,  ia[4], ib[4], w[4]);
        transpose_kernel<unsigned short, float><<<dim3(NBATCH / 32, (1000 + 31) / 32), tb, 0, stream>>>(
            h4T, (float*)d_out, 1000, NBATCH);
    }
}

// Round 5
// 265.388 us; speedup vs baseline: 1.4518x; 1.4518x over previous
//
#include <hip/hip_runtime.h>

// LogicGateNetwork: 5 layers of per-neuron 2-input soft logic gates.
// Activations TRANSPOSED ([dim][BATCH]) so per-neuron column gathers are
// coalesced contiguous row reads. Intermediates stored as IEEE fp16
// (values provably in [0,1]; rel err ~5e-4 << bf16 compare floor).
// Compute stays fp32.

#define NBATCH 2048

typedef __attribute__((ext_vector_type(8))) _Float16 half8;
typedef __attribute__((ext_vector_type(2))) _Float16 half2v;

// GATE_COEF (16 gates x 4 coefficients), row-major.
__device__ __constant__ float GC_dev[64] = {
    0, 0, 0, 0,   0, 0, 0, 1,   0, 1, 0, -1,  0, 1, 0, 0,
    0, 0, 1, -1,  0, 0, 1, 0,   0, 1, 1, -2,  0, 1, 1, -1,
    1, -1, -1, 1, 1, -1, -1, 2, 1, 0, -1, 0,  1, 0, -1, 1,
    1, -1, 0, 0,  1, -1, 0, 1,  1, 0, 0, -1,  1, 0, 0, 0
};

// coef = softmax(w_row) @ GATE_COEF (4 floats into sc[0..3]).
__device__ __forceinline__ void compute_coef(const float* __restrict__ wrow,
                                             float* __restrict__ sc) {
    float v[16];
#pragma unroll
    for (int g = 0; g < 16; ++g) v[g] = wrow[g];
    float m = v[0];
#pragma unroll
    for (int g = 1; g < 16; ++g) m = fmaxf(m, v[g]);
    float s = 0.f;
#pragma unroll
    for (int g = 0; g < 16; ++g) { v[g] = __expf(v[g] - m); s += v[g]; }
    float inv = 1.f / s;
    float c0 = 0.f, c1 = 0.f, c2 = 0.f, c3 = 0.f;
#pragma unroll
    for (int g = 0; g < 16; ++g) {
        c0 += v[g] * GC_dev[g * 4 + 0];
        c1 += v[g] * GC_dev[g * 4 + 1];
        c2 += v[g] * GC_dev[g * 4 + 2];
        c3 += v[g] * GC_dev[g * 4 + 3];
    }
    sc[0] = c0 * inv; sc[1] = c1 * inv; sc[2] = c2 * inv; sc[3] = c3 * inv;
}

// x [NBATCH][8192] fp32 -> xT [8192][NBATCH] fp16. Tile: 64 batch x 32 feat.
// Both global phases keep >=128B contiguous per 32 lanes.
__global__ __launch_bounds__(256) void transpose_in_kernel(
    const float* __restrict__ in, _Float16* __restrict__ out) {
    __shared__ float tile[64][33];
    int bx = blockIdx.x * 32;   // feature tile
    int by = blockIdx.y * 64;   // batch tile
    int tx = threadIdx.x, ty = threadIdx.y;  // (32,8)
#pragma unroll
    for (int i = 0; i < 8; ++i) {
        int r = ty + 8 * i;
        tile[r][tx] = in[(size_t)(by + r) * 8192 + bx + tx];
    }
    __syncthreads();
#pragma unroll
    for (int i = 0; i < 4; ++i) {
        int oc = ty + 8 * i;    // feature within tile
        int ob = 2 * tx;        // batch offset within tile
        half2v h;
        h.x = (_Float16)tile[ob][oc];
        h.y = (_Float16)tile[ob + 1][oc];
        *(half2v*)&out[(size_t)(bx + oc) * NBATCH + by + ob] = h;
    }
}

// Generic small transpose: in[rows][cols] -> out[cols][rows]. Block (32,8).
__global__ void transpose_out_kernel(const _Float16* __restrict__ in,
                                     float* __restrict__ out, int rows, int cols) {
    __shared__ float tile[32][33];
    int bx = blockIdx.x * 32, by = blockIdx.y * 32;
    int tx = threadIdx.x, ty = threadIdx.y;
#pragma unroll
    for (int i = 0; i < 32; i += 8) {
        int r = by + ty + i, c = bx + tx;
        if (r < rows && c < cols) tile[ty + i][tx] = (float)in[(size_t)r * cols + c];
    }
    __syncthreads();
#pragma unroll
    for (int i = 0; i < 32; i += 8) {
        int oc = bx + ty + i;   // output row = input col
        int orr = by + tx;      // output col = input row
        if (oc < cols && orr < rows)
            out[(size_t)oc * rows + orr] = tile[tx][ty + i];
    }
}

// One block per output neuron j; 256 threads x 8 batch elems (16B loads).
// in/out: [dim][NBATCH] fp16 activations.
__global__ __launch_bounds__(256) void logic_layer_kernel(
    const _Float16* __restrict__ in, _Float16* __restrict__ out,
    const int* __restrict__ ia, const int* __restrict__ ib,
    const float* __restrict__ w) {
    __shared__ float sc[4];
    int j = blockIdx.x;
    int t = threadIdx.x;  // 0..255
    if (t == 0) compute_coef(w + (size_t)j * 16, sc);
    int ja = ia[j];
    int jb = ib[j];

    const half8* ra = (const half8*)(in + (size_t)ja * NBATCH);
    const half8* rb = (const half8*)(in + (size_t)jb * NBATCH);
    half8 av = ra[t];
    half8 bv = rb[t];
    __syncthreads();
    float c0 = sc[0], c1 = sc[1], c2 = sc[2], c3 = sc[3];

    half8 ov;
#pragma unroll
    for (int k = 0; k < 8; ++k) {
        float a = (float)av[k];
        float b = (float)bv[k];
        ov[k] = (_Float16)fmaf(c3, a * b, fmaf(c2, b, fmaf(c1, a, c0)));
    }
    ((half8*)(out + (size_t)j * NBATCH))[t] = ov;
}

extern "C" void kernel_launch(void* const* d_in, const int* in_sizes, int n_in,
                              void* d_out, int out_size, void* d_ws, size_t ws_size,
                              hipStream_t stream) {
    // Input dict order: x, then (w_i, ia_i, ib_i) for i=0..4.
    const float* x = (const float*)d_in[0];
    const float* w[5];
    const int* ia[5];
    const int* ib[5];
    for (int i = 0; i < 5; ++i) {
        w[i]  = (const float*)d_in[1 + 3 * i];
        ia[i] = (const int*)d_in[2 + 3 * i];
        ib[i] = (const int*)d_in[3 + 3 * i];
    }

    // Workspace: 2 x 64 MiB fp16 ping-pong buffers (128 MiB total).
    //   xT  (8192x2048 fp16, 32 MiB) aliases bufB (dead once layer 1 writes bufB)
    //   h4T (1000x2048 fp16,  4 MiB) aliases bufA (bufA last read by layer 3)
    char* ws = (char*)d_ws;
    const size_t bufBytes = (size_t)16384 * NBATCH * sizeof(_Float16);  // 64 MiB
    _Float16* bufA = (_Float16*)ws;
    _Float16* bufB = (_Float16*)(ws + bufBytes);
    _Float16* xT  = bufB;
    _Float16* h4T = bufA;

    // 1) Transpose input x: (2048 x 8192) fp32 -> (8192 x 2048) fp16.
    transpose_in_kernel<<<dim3(8192 / 32, NBATCH / 64), dim3(32, 8), 0, stream>>>(x, xT);

    // 2) Five gather layers in transposed space (ping-pong bufA/bufB).
    logic_layer_kernel<<<16384, 256, 0, stream>>>(xT,   bufA, ia[0], ib[0], w[0]);
    logic_layer_kernel<<<16384, 256, 0, stream>>>(bufA, bufB, ia[1], ib[1], w[1]);
    logic_layer_kernel<<<16384, 256, 0, stream>>>(bufB, bufA, ia[2], ib[2], w[2]);
    logic_layer_kernel<<<16384, 256, 0, stream>>>(bufA, bufB, ia[3], ib[3], w[3]);
    logic_layer_kernel<<<1000,  256, 0, stream>>>(bufB, h4T,  ia[4], ib[4], w[4]);

    // 3) Transpose result (1000 x 2048) fp16 -> d_out (2048 x 1000) fp32.
    transpose_out_kernel<<<dim3(NBATCH / 32, (1000 + 31) / 32), dim3(32, 8), 0, stream>>>(
        h4T, (float*)d_out, 1000, NBATCH);
}

// Round 6
// 205.689 us; speedup vs baseline: 1.8731x; 1.2902x over previous
//
#include <hip/hip_runtime.h>

// LogicGateNetwork, fully fused: one block = one batch row; all 5 gather
// layers computed in LDS (feature gathers are batch-independent).
// Intermediates never touch HBM. Per-neuron records (softmax coefs + packed
// indices) precomputed into a 0.78 MB L2-resident table by a prep kernel.

#define NBATCH 2048
#define IN_DIM 8192
#define HID 16384
#define OUT_DIM 1000
#define NTOT (4 * HID + OUT_DIM)   // 66536 neurons total

typedef __attribute__((ext_vector_type(4))) _Float16 half4;

// GATE_COEF (16 gates x 4 coefficients), row-major.
__device__ __constant__ float GC_dev[64] = {
    0, 0, 0, 0,   0, 0, 0, 1,   0, 1, 0, -1,  0, 1, 0, 0,
    0, 0, 1, -1,  0, 0, 1, 0,   0, 1, 1, -2,  0, 1, 1, -1,
    1, -1, -1, 1, 1, -1, -1, 2, 1, 0, -1, 0,  1, 0, -1, 1,
    1, -1, 0, 0,  1, -1, 0, 1,  1, 0, 0, -1,  1, 0, 0, 0
};

struct PrepArgs {
    const float* w[5];
    const int* ia[5];
    const int* ib[5];
};

// One thread per neuron: coef = softmax(w_row) @ GATE_COEF -> half4,
// idx = ia | (ib<<16). Layer boundaries are multiples of 256, so every
// 256-thread block is within one layer (uniform branching).
__global__ __launch_bounds__(256) void prep_kernel(
    PrepArgs args, half4* __restrict__ coefT, unsigned int* __restrict__ idxT) {
    int g = blockIdx.x * 256 + threadIdx.x;
    if (g >= NTOT) return;
    int l = (g < 4 * HID) ? (g >> 14) : 4;
    int j = g - l * HID;

    const float* wrow = args.w[l] + (size_t)j * 16;
    float v[16];
    const float4* w4 = (const float4*)wrow;
#pragma unroll
    for (int i = 0; i < 4; ++i) {
        float4 t = w4[i];
        v[4 * i + 0] = t.x; v[4 * i + 1] = t.y; v[4 * i + 2] = t.z; v[4 * i + 3] = t.w;
    }
    float m = v[0];
#pragma unroll
    for (int g2 = 1; g2 < 16; ++g2) m = fmaxf(m, v[g2]);
    float s = 0.f;
#pragma unroll
    for (int g2 = 0; g2 < 16; ++g2) { v[g2] = __expf(v[g2] - m); s += v[g2]; }
    float inv = 1.f / s;
    float c0 = 0.f, c1 = 0.f, c2 = 0.f, c3 = 0.f;
#pragma unroll
    for (int g2 = 0; g2 < 16; ++g2) {
        c0 += v[g2] * GC_dev[g2 * 4 + 0];
        c1 += v[g2] * GC_dev[g2 * 4 + 1];
        c2 += v[g2] * GC_dev[g2 * 4 + 2];
        c3 += v[g2] * GC_dev[g2 * 4 + 3];
    }
    half4 c;
    c[0] = (_Float16)(c0 * inv); c[1] = (_Float16)(c1 * inv);
    c[2] = (_Float16)(c2 * inv); c[3] = (_Float16)(c3 * inv);
    coefT[g] = c;
    idxT[g] = (unsigned int)args.ia[l][j] | ((unsigned int)args.ib[l][j] << 16);
}

// Fused network: block b owns batch row b. LDS = 64KB: two 16384-entry fp16
// buffers (lo=[0,16384), hi=[16384,32768)); x staged into lo[0..8192).
// L0: lo->hi, L1: hi->lo, L2: lo->hi, L3: hi->lo, L4: lo->global.
__global__ __launch_bounds__(512) void fused_kernel(
    const float* __restrict__ x, const half4* __restrict__ coefT,
    const unsigned int* __restrict__ idxT, float* __restrict__ out) {
    __shared__ _Float16 lds[2 * HID];   // 65536 B
    int b = blockIdx.x;
    int t = threadIdx.x;  // 0..511

    // Stage x[b][:] (fp32, coalesced 16B/lane) -> lds[0..8192) fp16.
    const float4* xr = (const float4*)(x + (size_t)b * IN_DIM);
#pragma unroll
    for (int i = 0; i < 4; ++i) {
        int j = i * 2048 + t * 4;
        float4 v = xr[i * 512 + t];
        half4 h;
        h[0] = (_Float16)v.x; h[1] = (_Float16)v.y;
        h[2] = (_Float16)v.z; h[3] = (_Float16)v.w;
        *(half4*)&lds[j] = h;
    }
    __syncthreads();

    int inBase = 0, outBase = HID;
    int tabOfs = 0;
#pragma unroll
    for (int l = 0; l < 4; ++l) {
#pragma unroll 4
        for (int j = t; j < HID; j += 512) {
            unsigned int idx = idxT[tabOfs + j];
            half4 c = coefT[tabOfs + j];
            float a = (float)lds[inBase + (idx & 0xFFFFu)];
            float bb = (float)lds[inBase + (idx >> 16)];
            float r = fmaf((float)c[3], a * bb,
                      fmaf((float)c[2], bb,
                      fmaf((float)c[1], a, (float)c[0])));
            lds[outBase + j] = (_Float16)r;
        }
        tabOfs += HID;
        int tmp = inBase; inBase = outBase; outBase = tmp;
        __syncthreads();
    }

    // Final layer (1000 neurons) -> global, coalesced fp32 stores.
    // After 4 swaps inBase == 0.
    for (int j = t; j < OUT_DIM; j += 512) {
        unsigned int idx = idxT[tabOfs + j];
        half4 c = coefT[tabOfs + j];
        float a = (float)lds[idx & 0xFFFFu];
        float bb = (float)lds[idx >> 16];
        float r = fmaf((float)c[3], a * bb,
                  fmaf((float)c[2], bb,
                  fmaf((float)c[1], a, (float)c[0])));
        out[(size_t)b * OUT_DIM + j] = r;
    }
}

extern "C" void kernel_launch(void* const* d_in, const int* in_sizes, int n_in,
                              void* d_out, int out_size, void* d_ws, size_t ws_size,
                              hipStream_t stream) {
    // Input dict order: x, then (w_i, ia_i, ib_i) for i=0..4.
    const float* x = (const float*)d_in[0];
    PrepArgs args;
    for (int i = 0; i < 5; ++i) {
        args.w[i]  = (const float*)d_in[1 + 3 * i];
        args.ia[i] = (const int*)d_in[2 + 3 * i];
        args.ib[i] = (const int*)d_in[3 + 3 * i];
    }

    // Workspace: packed neuron tables (re-built every call; ws is re-poisoned).
    char* ws = (char*)d_ws;
    half4* coefT = (half4*)ws;                                   // 66536 * 8B
    size_t coefBytes = ((size_t)NTOT * 8 + 255) & ~(size_t)255;
    unsigned int* idxT = (unsigned int*)(ws + coefBytes);        // 66536 * 4B

    prep_kernel<<<(NTOT + 255) / 256, 256, 0, stream>>>(args, coefT, idxT);
    fused_kernel<<<NBATCH, 512, 0, stream>>>(x, coefT, idxT, (float*)d_out);
}

// Round 8
// 175.644 us; speedup vs baseline: 2.1935x; 1.1711x over previous
//
#include <hip/hip_runtime.h>

// LogicGateNetwork, fully fused, batch-paired: one block = TWO batch rows,
// activations stored as half2 (pair of batch elems) in LDS so every random
// gather read serves 2 batch elements -> LDS pipe work (the measured
// bottleneck: 2.15e7 bank-conflict cycles) halves, as does L2 table traffic.
// 128 KB dynamic LDS (2 x 16384 half2 ping-pong), 1024 threads/block.

#define NBATCH 2048
#define IN_DIM 8192
#define HID 16384
#define OUT_DIM 1000
#define NTOT (4 * HID + OUT_DIM)   // 66536 neurons total

typedef __attribute__((ext_vector_type(4))) _Float16 half4;
typedef __attribute__((ext_vector_type(2))) _Float16 half2v;

// GATE_COEF (16 gates x 4 coefficients), row-major.
__device__ __constant__ float GC_dev[64] = {
    0, 0, 0, 0,   0, 0, 0, 1,   0, 1, 0, -1,  0, 1, 0, 0,
    0, 0, 1, -1,  0, 0, 1, 0,   0, 1, 1, -2,  0, 1, 1, -1,
    1, -1, -1, 1, 1, -1, -1, 2, 1, 0, -1, 0,  1, 0, -1, 1,
    1, -1, 0, 0,  1, -1, 0, 1,  1, 0, 0, -1,  1, 0, 0, 0
};

struct PrepArgs {
    const float* w[5];
    const int* ia[5];
    const int* ib[5];
};

// One thread per neuron: coef = softmax(w_row) @ GATE_COEF -> half4,
// idx = ia | (ib<<16).
__global__ __launch_bounds__(256) void prep_kernel(
    PrepArgs args, half4* __restrict__ coefT, unsigned int* __restrict__ idxT) {
    int g = blockIdx.x * 256 + threadIdx.x;
    if (g >= NTOT) return;
    int l = (g < 4 * HID) ? (g >> 14) : 4;
    int j = g - l * HID;

    const float* wrow = args.w[l] + (size_t)j * 16;
    float v[16];
    const float4* w4 = (const float4*)wrow;
#pragma unroll
    for (int i = 0; i < 4; ++i) {
        float4 t = w4[i];
        v[4 * i + 0] = t.x; v[4 * i + 1] = t.y; v[4 * i + 2] = t.z; v[4 * i + 3] = t.w;
    }
    float m = v[0];
#pragma unroll
    for (int g2 = 1; g2 < 16; ++g2) m = fmaxf(m, v[g2]);
    float s = 0.f;
#pragma unroll
    for (int g2 = 0; g2 < 16; ++g2) { v[g2] = __expf(v[g2] - m); s += v[g2]; }
    float inv = 1.f / s;
    float c0 = 0.f, c1 = 0.f, c2 = 0.f, c3 = 0.f;
#pragma unroll
    for (int g2 = 0; g2 < 16; ++g2) {
        c0 += v[g2] * GC_dev[g2 * 4 + 0];
        c1 += v[g2] * GC_dev[g2 * 4 + 1];
        c2 += v[g2] * GC_dev[g2 * 4 + 2];
        c3 += v[g2] * GC_dev[g2 * 4 + 3];
    }
    half4 c;
    c[0] = (_Float16)(c0 * inv); c[1] = (_Float16)(c1 * inv);
    c[2] = (_Float16)(c2 * inv); c[3] = (_Float16)(c3 * inv);
    coefT[g] = c;
    idxT[g] = (unsigned int)args.ia[l][j] | ((unsigned int)args.ib[l][j] << 16);
}

// Block bp owns batch rows 2*bp and 2*bp+1. Dynamic LDS: half2v[2*HID]
// (128 KB): entries [0,HID) and [HID,2*HID) ping-pong; each entry holds the
// activation of one feature for BOTH batch rows. Compute in fp32.
__global__ __launch_bounds__(1024) void fused_kernel(
    const float* __restrict__ x, const half4* __restrict__ coefT,
    const unsigned int* __restrict__ idxT, float* __restrict__ out) {
    extern __shared__ half2v lds[];   // 2 * HID entries = 131072 B
    int bp = blockIdx.x;
    int t = threadIdx.x;  // 0..1023
    int b0 = 2 * bp, b1 = 2 * bp + 1;

    // Stage x rows b0,b1 (fp32, 16B/lane coalesced) -> lds[0..8192) half2.
    const float4* xr0 = (const float4*)(x + (size_t)b0 * IN_DIM);
    const float4* xr1 = (const float4*)(x + (size_t)b1 * IN_DIM);
#pragma unroll
    for (int i = 0; i < 2; ++i) {
        int e = i * 1024 + t;        // float4 index; feature f = 4*e
        float4 v0 = xr0[e];
        float4 v1 = xr1[e];
        half2v h0 = {(_Float16)v0.x, (_Float16)v1.x};
        half2v h1 = {(_Float16)v0.y, (_Float16)v1.y};
        half2v h2 = {(_Float16)v0.z, (_Float16)v1.z};
        half2v h3 = {(_Float16)v0.w, (_Float16)v1.w};
        lds[4 * e + 0] = h0;
        lds[4 * e + 1] = h1;
        lds[4 * e + 2] = h2;
        lds[4 * e + 3] = h3;
    }
    __syncthreads();

    int inW = 0, outW = HID;
    int tab = 0;
#pragma unroll
    for (int l = 0; l < 4; ++l) {
#pragma unroll 4
        for (int k = 0; k < HID / 1024; ++k) {
            int j = k * 1024 + t;
            unsigned int idx = idxT[tab + j];
            half4 c = coefT[tab + j];
            half2v ap = lds[inW + (idx & 0xFFFFu)];
            half2v bq = lds[inW + (idx >> 16)];
            float c0 = (float)c[0], c1 = (float)c[1];
            float c2 = (float)c[2], c3 = (float)c[3];
            float a0 = (float)ap[0], a1 = (float)ap[1];
            float q0 = (float)bq[0], q1 = (float)bq[1];
            float r0 = fmaf(c3, a0 * q0, fmaf(c2, q0, fmaf(c1, a0, c0)));
            float r1 = fmaf(c3, a1 * q1, fmaf(c2, q1, fmaf(c1, a1, c0)));
            half2v o = {(_Float16)r0, (_Float16)r1};
            lds[outW + j] = o;
        }
        tab += HID;
        int tmp = inW; inW = outW; outW = tmp;
        __syncthreads();
    }

    // Final layer (1000 neurons) -> global fp32, coalesced per row.
    // After 4 swaps inW == 0.
    if (t < OUT_DIM) {
        unsigned int idx = idxT[tab + t];
        half4 c = coefT[tab + t];
        half2v ap = lds[idx & 0xFFFFu];
        half2v bq = lds[idx >> 16];
        float c0 = (float)c[0], c1 = (float)c[1];
        float c2 = (float)c[2], c3 = (float)c[3];
        float a0 = (float)ap[0], a1 = (float)ap[1];
        float q0 = (float)bq[0], q1 = (float)bq[1];
        out[(size_t)b0 * OUT_DIM + t] =
            fmaf(c3, a0 * q0, fmaf(c2, q0, fmaf(c1, a0, c0)));
        out[(size_t)b1 * OUT_DIM + t] =
            fmaf(c3, a1 * q1, fmaf(c2, q1, fmaf(c1, a1, c0)));
    }
}

extern "C" void kernel_launch(void* const* d_in, const int* in_sizes, int n_in,
                              void* d_out, int out_size, void* d_ws, size_t ws_size,
                              hipStream_t stream) {
    // Input dict order: x, then (w_i, ia_i, ib_i) for i=0..4.
    const float* x = (const float*)d_in[0];
    PrepArgs args;
    for (int i = 0; i < 5; ++i) {
        args.w[i]  = (const float*)d_in[1 + 3 * i];
        args.ia[i] = (const int*)d_in[2 + 3 * i];
        args.ib[i] = (const int*)d_in[3 + 3 * i];
    }

    // Workspace: packed neuron tables (~0.8 MB; rebuilt every call).
    char* ws = (char*)d_ws;
    half4* coefT = (half4*)ws;                                   // NTOT * 8B
    size_t coefBytes = ((size_t)NTOT * 8 + 255) & ~(size_t)255;
    unsigned int* idxT = (unsigned int*)(ws + coefBytes);        // NTOT * 4B

    prep_kernel<<<(NTOT + 255) / 256, 256, 0, stream>>>(args, coefT, idxT);
    fused_kernel<<<NBATCH / 2, 1024, 2 * HID * sizeof(half2v), stream>>>(
        x, coefT, idxT, (float*)d_out);
}